// Round 3
// baseline (352.964 us; speedup 1.0000x reference)
//
#include <hip/hip_runtime.h>
#include <math.h>

#define HIDDEN 128
#define NBLOCKS 512
#define NTHREADS 1024
#define BMAP_WORDS 6272   // 200704 bits >= 200000 nodes

// ---------------------------------------------------------------------------
// Single fused kernel:
//   phase A (per block, redundant): fc = [x;X[s];X[p]], q = fc@Wq,
//            qk = (Wk@q)/sqrt(128)  -> LDS (L2-resident weights, ~1-2 us)
//            + visited bitmap in LDS (duplicate-safe atomicOr)
//   phase B: grid-strided streaming online-softmax + weighted row sum over X
//   phase C: block partial -> ws; threadfence + atomic counter; LAST block
//            combines partials and does h=pvec@Wv, out=h@Wo.
// ---------------------------------------------------------------------------
__global__ __launch_bounds__(NTHREADS, 8) void fused_kernel(
    const float* __restrict__ X, const float* __restrict__ x,
    const float* __restrict__ Wq, const float* __restrict__ Wk,
    const float* __restrict__ Wv, const float* __restrict__ Wo,
    const int* __restrict__ visited, int nv,
    const int* __restrict__ startp, const int* __restrict__ prevp,
    float* __restrict__ Mb, float* __restrict__ Sb, float* __restrict__ Gb,
    unsigned* __restrict__ counter,
    float* __restrict__ out, int n)
{
    __shared__ unsigned bmap[BMAP_WORDS];       // 25.0 KB
    __shared__ float fc[384];
    __shared__ float qpart[8][HIDDEN];          // 4 KB (reused in finish)
    __shared__ float qv[HIDDEN];                // reused as pvec
    __shared__ float qk_s[HIDDEN];              // reused as hvec
    __shared__ float m_arr[32], s_arr[32];
    __shared__ float g_all[32 * HIDDEN];        // 16 KB (reused as e/red)
    __shared__ bool  is_last;

    const int tid  = threadIdx.x;
    const int lane = tid & 63;
    const int sub  = lane & 31;                 // lane within half-wave
    const int half = (lane >> 5) & 1;
    const int col  = tid & (HIDDEN - 1);
    const int seg  = tid >> 7;                  // 0..7

    // ---------------- phase A: bitmap zero + fc load ----------------
    const int nwords = (n + 31) >> 5;
    for (int w = tid; w < nwords; w += NTHREADS) bmap[w] = 0u;
    if (tid < 128)       fc[tid] = x[tid];
    else if (tid < 256)  fc[tid] = X[(size_t)startp[0] * HIDDEN + (tid - 128)];
    else if (tid < 384)  fc[tid] = X[(size_t)prevp[0]  * HIDDEN + (tid - 256)];
    __syncthreads();

    // scatter visited bits (safe: next barrier is 2 syncs below)
    for (int i = tid; i < nv; i += NTHREADS) {
        const int v = visited[i];
        atomicOr(&bmap[v >> 5], 1u << (v & 31));
    }

    // q[col] = sum_m fc[m]*Wq[m,col]; m split into 8 segs of 48
    {
        float acc = 0.f;
        const int m0 = seg * 48;
        #pragma unroll 8
        for (int m = 0; m < 48; ++m)
            acc += fc[m0 + m] * Wq[(size_t)(m0 + m) * HIDDEN + col];
        qpart[seg][col] = acc;
    }
    __syncthreads();
    if (tid < HIDDEN) {
        float s = 0.f;
        #pragma unroll
        for (int k = 0; k < 8; ++k) s += qpart[k][tid];
        qv[tid] = s;
    }
    __syncthreads();

    // qk_s[row] = (Wk[row,:].qv)/sqrt(128); half-wave per row, 32 hw in block
    {
        const int hw32 = tid >> 5;              // 0..31
        const float4 qv4 = *(const float4*)(&qv[sub << 2]);
        for (int row = hw32; row < HIDDEN; row += 32) {
            const float4 wk4 = *(const float4*)(Wk + (size_t)row * HIDDEN + (sub << 2));
            float p = wk4.x * qv4.x + wk4.y * qv4.y + wk4.z * qv4.z + wk4.w * qv4.w;
            #pragma unroll
            for (int off = 16; off >= 1; off >>= 1)
                p += __shfl_xor(p, off, 64);
            if (sub == 0) qk_s[row] = p * 0.08838834764831845f;
        }
    }
    __syncthreads();   // qk_s + bmap ready

    // ---------------- phase B: streaming online softmax ----------------
    const int wavesPerBlock = NTHREADS >> 6;                 // 16
    const int gw  = blockIdx.x * wavesPerBlock + (tid >> 6);
    const int vhw = gw * 2 + half;
    const int T   = NBLOCKS * wavesPerBlock * 2;

    const float4 qkv = *(const float4*)(&qk_s[sub << 2]);

    float m = -INFINITY, s = 0.f;
    float g0 = 0.f, g1 = 0.f, g2 = 0.f, g3 = 0.f;

    for (int r = vhw; r < n; r += T) {
        const float4 xv = *(const float4*)(X + (size_t)r * HIDDEN + (sub << 2));
        float p = xv.x * qkv.x + xv.y * qkv.y + xv.z * qkv.z + xv.w * qkv.w;
        #pragma unroll
        for (int off = 16; off >= 1; off >>= 1)
            p += __shfl_xor(p, off, 64);
        const float maskv = ((bmap[r >> 5] >> (r & 31)) & 1u) ? 0.f : 1.f;
        const float u = p + maskv;
        const float mn    = fmaxf(m, u);
        const float scale = __expf(m - mn);   // exp(-inf)=0 on first iter
        const float w     = __expf(u - mn);
        s  = s  * scale + w;
        g0 = g0 * scale + w * xv.x;
        g1 = g1 * scale + w * xv.y;
        g2 = g2 * scale + w * xv.z;
        g3 = g3 * scale + w * xv.w;
        m  = mn;
    }

    // ---------------- phase C: block combine -> partial ----------------
    const int hw = tid >> 5;                   // half-wave idx 0..31
    *(float4*)(&g_all[hw * HIDDEN + (sub << 2)]) = make_float4(g0, g1, g2, g3);
    if (sub == 0) { m_arr[hw] = m; s_arr[hw] = s; }
    __syncthreads();

    float mb = m_arr[0];
    #pragma unroll
    for (int h = 1; h < 32; ++h) mb = fmaxf(mb, m_arr[h]);

    if (tid < HIDDEN) {
        float G = 0.f;
        #pragma unroll 4
        for (int h = 0; h < 32; ++h)
            G += g_all[h * HIDDEN + tid] * __expf(m_arr[h] - mb);
        Gb[(size_t)blockIdx.x * HIDDEN + tid] = G;
    } else if (tid == HIDDEN) {
        float S = 0.f;
        #pragma unroll
        for (int h = 0; h < 32; ++h) S += s_arr[h] * __expf(m_arr[h] - mb);
        Sb[blockIdx.x] = S;
        Mb[blockIdx.x] = mb;
    }

    // ---------------- last-block-done handoff ----------------
    __threadfence();            // release: partials visible device-wide
    __syncthreads();
    if (tid == 0) {
        const unsigned prev = atomicAdd(counter, 1u);
        is_last = (prev == (unsigned)(NBLOCKS - 1));
    }
    __syncthreads();
    if (!is_last) return;
    __threadfence();            // acquire: see all blocks' partials

    // ---------------- finish (runs in exactly one block) ----------------
    float* e   = g_all;                        // [NBLOCKS] alias
    float* red = g_all + NBLOCKS;              // [NBLOCKS] alias

    const float mt = (tid < NBLOCKS) ? Mb[tid] : -INFINITY;
    if (tid < NBLOCKS) red[tid] = mt;
    __syncthreads();
    for (int st = NBLOCKS / 2; st >= 1; st >>= 1) {
        if (tid < st) red[tid] = fmaxf(red[tid], red[tid + st]);
        __syncthreads();
    }
    const float M = red[0];
    __syncthreads();

    if (tid < NBLOCKS) {
        const float eb = __expf(mt - M);
        e[tid]   = eb;
        red[tid] = Sb[tid] * eb;
    }
    __syncthreads();
    for (int st = NBLOCKS / 2; st >= 1; st >>= 1) {
        if (tid < st) red[tid] += red[tid + st];
        __syncthreads();
    }
    const float S = red[0];
    __syncthreads();

    // pvec[col] = (sum_b Gb[b,col]*e[b]) / S ; b split into 8 segs of 64
    {
        float acc = 0.f;
        const int b0 = seg * (NBLOCKS / 8);
        #pragma unroll 8
        for (int b = 0; b < NBLOCKS / 8; ++b)
            acc += Gb[(size_t)(b0 + b) * HIDDEN + col] * e[b0 + b];
        qpart[seg][col] = acc;
    }
    __syncthreads();
    if (tid < HIDDEN) {
        float G = 0.f;
        #pragma unroll
        for (int k = 0; k < 8; ++k) G += qpart[k][tid];
        qv[tid] = G / S;                       // pvec
    }
    __syncthreads();

    // hvec[col] = sum_m pvec[m]*Wv[m,col]; m split into 8 segs of 16
    {
        float acc = 0.f;
        const int m0 = seg * 16;
        #pragma unroll
        for (int mm = 0; mm < 16; ++mm)
            acc += qv[m0 + mm] * Wv[(size_t)(m0 + mm) * HIDDEN + col];
        qpart[seg][col] = acc;
    }
    __syncthreads();
    if (tid < HIDDEN) {
        float h = 0.f;
        #pragma unroll
        for (int k = 0; k < 8; ++k) h += qpart[k][tid];
        qk_s[tid] = h;                         // hvec
    }
    __syncthreads();

    // out[col] = sum_m hvec[m]*Wo[m,col]
    {
        float acc = 0.f;
        const int m0 = seg * 16;
        #pragma unroll
        for (int mm = 0; mm < 16; ++mm)
            acc += qk_s[m0 + mm] * Wo[(size_t)(m0 + mm) * HIDDEN + col];
        qpart[seg][col] = acc;
    }
    __syncthreads();
    if (tid < HIDDEN) {
        float o = 0.f;
        #pragma unroll
        for (int k = 0; k < 8; ++k) o += qpart[k][tid];
        out[tid] = o;
    }
}

// ---------------------------------------------------------------------------
extern "C" void kernel_launch(void* const* d_in, const int* in_sizes, int n_in,
                              void* d_out, int out_size, void* d_ws, size_t ws_size,
                              hipStream_t stream)
{
    const float* X       = (const float*)d_in[0];
    const float* x       = (const float*)d_in[1];
    const float* Wq      = (const float*)d_in[2];
    const float* Wk      = (const float*)d_in[3];
    const float* Wv      = (const float*)d_in[4];
    const float* Wo      = (const float*)d_in[5];
    const int*   visited = (const int*)d_in[6];
    const int*   startp  = (const int*)d_in[7];
    const int*   prevp   = (const int*)d_in[8];

    const int n  = in_sizes[0] / HIDDEN;   // 200000
    const int nv = in_sizes[6];            // 1024

    float* ws = (float*)d_ws;
    float* Mb = ws;                                    // NBLOCKS
    float* Sb = Mb + NBLOCKS;                          // NBLOCKS
    float* Gb = Sb + NBLOCKS;                          // NBLOCKS*128
    unsigned* counter = (unsigned*)(Gb + (size_t)NBLOCKS * HIDDEN);

    hipMemsetAsync(counter, 0, sizeof(unsigned), stream);
    fused_kernel<<<NBLOCKS, NTHREADS, 0, stream>>>(
        X, x, Wq, Wk, Wv, Wo, visited, nv, startp, prevp,
        Mb, Sb, Gb, counter, (float*)d_out, n);
}

// Round 4
// 243.741 us; speedup vs baseline: 1.4481x; 1.4481x over previous
//
#include <hip/hip_runtime.h>
#include <math.h>

#define HIDDEN 128
#define NBLOCKS 256
#define NTHREADS 1024
#define BMAP_WORDS 6272   // 200704 bits >= 200000 nodes

// ---------------------------------------------------------------------------
// Single fused kernel (round-4: fix VGPR squeeze, dual-row streaming):
//   phase A (per block, redundant): fc=[x;X[s];X[p]], q=fc@Wq,
//            qk=(Wk@q)/sqrt(128) -> LDS; visited bitmap in LDS (atomicOr)
//   phase B: grid-strided dual-row online-softmax + weighted row sum over X
//   phase C: block partial -> ws; threadfence + atomic counter; LAST block
//            combines partials and does h=pvec@Wv, out=h@Wo.
// __launch_bounds__(1024,4): 1 block/CU, VGPR cap 128 — round-3's (,8) forced
// VGPR=32 and serialized the hot loop (VALUBusy 4.6%, 200us). Do not lower.
// ---------------------------------------------------------------------------
__global__ __launch_bounds__(NTHREADS, 4) void fused_kernel(
    const float* __restrict__ X, const float* __restrict__ x,
    const float* __restrict__ Wq, const float* __restrict__ Wk,
    const float* __restrict__ Wv, const float* __restrict__ Wo,
    const int* __restrict__ visited, int nv,
    const int* __restrict__ startp, const int* __restrict__ prevp,
    float* __restrict__ Mb, float* __restrict__ Sb, float* __restrict__ Gb,
    unsigned* __restrict__ counter,
    float* __restrict__ out, int n)
{
    __shared__ unsigned bmap[BMAP_WORDS];       // 25.0 KB
    __shared__ float fc[384];
    __shared__ float qpart[8][HIDDEN];          // 4 KB (reused in finish)
    __shared__ float qv[HIDDEN];                // reused as pvec
    __shared__ float qk_s[HIDDEN];              // reused as hvec
    __shared__ float m_arr[32], s_arr[32];
    __shared__ float g_all[32 * HIDDEN];        // 16 KB (reused as e/red)
    __shared__ bool  is_last;

    const int tid  = threadIdx.x;
    const int lane = tid & 63;
    const int sub  = lane & 31;                 // lane within half-wave
    const int half = (lane >> 5) & 1;
    const int col  = tid & (HIDDEN - 1);
    const int seg  = tid >> 7;                  // 0..7

    // ---------------- phase A: bitmap zero + fc load ----------------
    const int nwords = (n + 31) >> 5;
    for (int w = tid; w < nwords; w += NTHREADS) bmap[w] = 0u;
    if (tid < 128)       fc[tid] = x[tid];
    else if (tid < 256)  fc[tid] = X[(size_t)startp[0] * HIDDEN + (tid - 128)];
    else if (tid < 384)  fc[tid] = X[(size_t)prevp[0]  * HIDDEN + (tid - 256)];
    __syncthreads();

    // scatter visited bits (bitmap consumed after the barrier below)
    for (int i = tid; i < nv; i += NTHREADS) {
        const int v = visited[i];
        atomicOr(&bmap[v >> 5], 1u << (v & 31));
    }

    // q[col] = sum_m fc[m]*Wq[m,col]; m split into 8 segs of 48
    {
        float acc = 0.f;
        const int m0 = seg * 48;
        #pragma unroll 8
        for (int m = 0; m < 48; ++m)
            acc += fc[m0 + m] * Wq[(size_t)(m0 + m) * HIDDEN + col];
        qpart[seg][col] = acc;
    }
    __syncthreads();
    if (tid < HIDDEN) {
        float s = 0.f;
        #pragma unroll
        for (int k = 0; k < 8; ++k) s += qpart[k][tid];
        qv[tid] = s;
    }
    __syncthreads();

    // qk_s[row] = (Wk[row,:].qv)/sqrt(128); half-wave per row
    {
        const int hw32 = tid >> 5;              // 0..31
        const float4 qv4 = *(const float4*)(&qv[sub << 2]);
        for (int row = hw32; row < HIDDEN; row += 32) {
            const float4 wk4 = *(const float4*)(Wk + (size_t)row * HIDDEN + (sub << 2));
            float p = wk4.x * qv4.x + wk4.y * qv4.y + wk4.z * qv4.z + wk4.w * qv4.w;
            #pragma unroll
            for (int off = 16; off >= 1; off >>= 1)
                p += __shfl_xor(p, off, 64);
            if (sub == 0) qk_s[row] = p * 0.08838834764831845f;
        }
    }
    __syncthreads();   // qk_s + bmap ready

    // ---------------- phase B: dual-row streaming online softmax ----------------
    const int wavesPerBlock = NTHREADS >> 6;                 // 16
    const int gw  = blockIdx.x * wavesPerBlock + (tid >> 6);
    const int vhw = gw * 2 + half;
    const int T   = NBLOCKS * wavesPerBlock * 2;             // 8192 half-waves

    const float4 qkv = *(const float4*)(&qk_s[sub << 2]);

    float m = -INFINITY, s = 0.f;
    float g0 = 0.f, g1 = 0.f, g2 = 0.f, g3 = 0.f;

    int r = vhw;
    for (; r + T < n; r += 2 * T) {
        const int r2 = r + T;
        const float4 xa = *(const float4*)(X + (size_t)r  * HIDDEN + (sub << 2));
        const float4 xb = *(const float4*)(X + (size_t)r2 * HIDDEN + (sub << 2));
        float pa = xa.x * qkv.x + xa.y * qkv.y + xa.z * qkv.z + xa.w * qkv.w;
        float pb = xb.x * qkv.x + xb.y * qkv.y + xb.z * qkv.z + xb.w * qkv.w;
        #pragma unroll
        for (int off = 16; off >= 1; off >>= 1) {
            pa += __shfl_xor(pa, off, 64);
            pb += __shfl_xor(pb, off, 64);
        }
        const float ma = ((bmap[r  >> 5] >> (r  & 31)) & 1u) ? 0.f : 1.f;
        const float mb_ = ((bmap[r2 >> 5] >> (r2 & 31)) & 1u) ? 0.f : 1.f;
        const float ua = pa + ma;
        const float ub = pb + mb_;
        const float mn    = fmaxf(m, fmaxf(ua, ub));
        const float scale = __expf(m - mn);   // exp(-inf)=0 on first iter
        const float wa    = __expf(ua - mn);
        const float wb    = __expf(ub - mn);
        s  = s  * scale + wa + wb;
        g0 = g0 * scale + wa * xa.x + wb * xb.x;
        g1 = g1 * scale + wa * xa.y + wb * xb.y;
        g2 = g2 * scale + wa * xa.z + wb * xb.z;
        g3 = g3 * scale + wa * xa.w + wb * xb.w;
        m  = mn;
    }
    if (r < n) {
        const float4 xa = *(const float4*)(X + (size_t)r * HIDDEN + (sub << 2));
        float pa = xa.x * qkv.x + xa.y * qkv.y + xa.z * qkv.z + xa.w * qkv.w;
        #pragma unroll
        for (int off = 16; off >= 1; off >>= 1)
            pa += __shfl_xor(pa, off, 64);
        const float ua = pa + (((bmap[r >> 5] >> (r & 31)) & 1u) ? 0.f : 1.f);
        const float mn    = fmaxf(m, ua);
        const float scale = __expf(m - mn);
        const float wa    = __expf(ua - mn);
        s  = s  * scale + wa;
        g0 = g0 * scale + wa * xa.x;
        g1 = g1 * scale + wa * xa.y;
        g2 = g2 * scale + wa * xa.z;
        g3 = g3 * scale + wa * xa.w;
        m  = mn;
    }

    // ---------------- phase C: block combine -> partial ----------------
    const int hw = tid >> 5;                   // half-wave idx 0..31
    *(float4*)(&g_all[hw * HIDDEN + (sub << 2)]) = make_float4(g0, g1, g2, g3);
    if (sub == 0) { m_arr[hw] = m; s_arr[hw] = s; }
    __syncthreads();

    float mbv = m_arr[0];
    #pragma unroll
    for (int h = 1; h < 32; ++h) mbv = fmaxf(mbv, m_arr[h]);

    if (tid < HIDDEN) {
        float G = 0.f;
        #pragma unroll 4
        for (int h = 0; h < 32; ++h)
            G += g_all[h * HIDDEN + tid] * __expf(m_arr[h] - mbv);
        Gb[(size_t)blockIdx.x * HIDDEN + tid] = G;
    } else if (tid == HIDDEN) {
        float S = 0.f;
        #pragma unroll
        for (int h = 0; h < 32; ++h) S += s_arr[h] * __expf(m_arr[h] - mbv);
        Sb[blockIdx.x] = S;
        Mb[blockIdx.x] = mbv;
    }

    // ---------------- last-block-done handoff ----------------
    __threadfence();            // release: partials visible device-wide
    __syncthreads();
    if (tid == 0) {
        const unsigned prev = atomicAdd(counter, 1u);
        is_last = (prev == (unsigned)(NBLOCKS - 1));
    }
    __syncthreads();
    if (!is_last) return;
    __threadfence();            // acquire: see all blocks' partials

    // ---------------- finish (runs in exactly one block) ----------------
    float* e   = g_all;                        // [NBLOCKS] alias
    float* red = g_all + NBLOCKS;              // [NBLOCKS] alias

    const float mt = (tid < NBLOCKS) ? Mb[tid] : -INFINITY;
    if (tid < NBLOCKS) red[tid] = mt;
    __syncthreads();
    for (int st = NBLOCKS / 2; st >= 1; st >>= 1) {
        if (tid < st) red[tid] = fmaxf(red[tid], red[tid + st]);
        __syncthreads();
    }
    const float M = red[0];
    __syncthreads();

    if (tid < NBLOCKS) {
        const float eb = __expf(mt - M);
        e[tid]   = eb;
        red[tid] = Sb[tid] * eb;
    }
    __syncthreads();
    for (int st = NBLOCKS / 2; st >= 1; st >>= 1) {
        if (tid < st) red[tid] += red[tid + st];
        __syncthreads();
    }
    const float S = red[0];
    __syncthreads();

    // pvec[col] = (sum_b Gb[b,col]*e[b]) / S ; b split into 8 segs
    {
        float acc = 0.f;
        const int b0 = seg * (NBLOCKS / 8);
        #pragma unroll 8
        for (int b = 0; b < NBLOCKS / 8; ++b)
            acc += Gb[(size_t)(b0 + b) * HIDDEN + col] * e[b0 + b];
        qpart[seg][col] = acc;
    }
    __syncthreads();
    if (tid < HIDDEN) {
        float G = 0.f;
        #pragma unroll
        for (int k = 0; k < 8; ++k) G += qpart[k][tid];
        qv[tid] = G / S;                       // pvec
    }
    __syncthreads();

    // hvec[col] = sum_m pvec[m]*Wv[m,col]; m split into 8 segs of 16
    {
        float acc = 0.f;
        const int m0 = seg * 16;
        #pragma unroll
        for (int mm = 0; mm < 16; ++mm)
            acc += qv[m0 + mm] * Wv[(size_t)(m0 + mm) * HIDDEN + col];
        qpart[seg][col] = acc;
    }
    __syncthreads();
    if (tid < HIDDEN) {
        float h = 0.f;
        #pragma unroll
        for (int k = 0; k < 8; ++k) h += qpart[k][tid];
        qk_s[tid] = h;                         // hvec
    }
    __syncthreads();

    // out[col] = sum_m hvec[m]*Wo[m,col]
    {
        float acc = 0.f;
        const int m0 = seg * 16;
        #pragma unroll
        for (int mm = 0; mm < 16; ++mm)
            acc += qk_s[m0 + mm] * Wo[(size_t)(m0 + mm) * HIDDEN + col];
        qpart[seg][col] = acc;
    }
    __syncthreads();
    if (tid < HIDDEN) {
        float o = 0.f;
        #pragma unroll
        for (int k = 0; k < 8; ++k) o += qpart[k][tid];
        out[tid] = o;
    }
}

// ---------------------------------------------------------------------------
extern "C" void kernel_launch(void* const* d_in, const int* in_sizes, int n_in,
                              void* d_out, int out_size, void* d_ws, size_t ws_size,
                              hipStream_t stream)
{
    const float* X       = (const float*)d_in[0];
    const float* x       = (const float*)d_in[1];
    const float* Wq      = (const float*)d_in[2];
    const float* Wk      = (const float*)d_in[3];
    const float* Wv      = (const float*)d_in[4];
    const float* Wo      = (const float*)d_in[5];
    const int*   visited = (const int*)d_in[6];
    const int*   startp  = (const int*)d_in[7];
    const int*   prevp   = (const int*)d_in[8];

    const int n  = in_sizes[0] / HIDDEN;   // 200000
    const int nv = in_sizes[6];            // 1024

    float* ws = (float*)d_ws;
    float* Mb = ws;                                    // NBLOCKS
    float* Sb = Mb + NBLOCKS;                          // NBLOCKS
    float* Gb = Sb + NBLOCKS;                          // NBLOCKS*128
    unsigned* counter = (unsigned*)(Gb + (size_t)NBLOCKS * HIDDEN);

    hipMemsetAsync(counter, 0, sizeof(unsigned), stream);
    fused_kernel<<<NBLOCKS, NTHREADS, 0, stream>>>(
        X, x, Wq, Wk, Wv, Wo, visited, nv, startp, prevp,
        Mb, Sb, Gb, counter, (float*)d_out, n);
}